// Round 4
// baseline (453.273 us; speedup 1.0000x reference)
//
#include <hip/hip_runtime.h>
#include <hip/hip_bf16.h>
#include <math.h>

#define BN 256
#define NN 2048
#define CC 64

// workspace float offsets (no memset: every region written before read)
#define WS_SUMQ 0                            // B*2*64  per-half masked q sums
#define WS_SUMM (WS_SUMQ + BN * 2 * 64)      // B*2     per-half mask sums
#define WS_V    (WS_SUMM + BN * 2)           // B*2*64  per-half p*v partials
#define WS_S    (WS_V + BN * 2 * 64)         // B*2*8   per-half p sums
#define WS_MASK (WS_S + BN * 2 * 8)          // B*2048  compact mask column

typedef __bf16 bf16x8 __attribute__((ext_vector_type(8)));
typedef float f32x4 __attribute__((ext_vector_type(4)));

// ---------------- K1: masked pool over N -------------------------------------
// Stream-count fix: 512 blocks x 1024 thr; each block owns ONE contiguous 256KB
// q_data slab (1024 rows = 16384 float4) swept as a single sequential front,
// 16 steps of 1024 float4 (16KB) each. Step i covers rows [i*64, i*64+64);
// thread tid handles float4 i*1024+tid -> row i*64+(tid>>4), chans (tid&15)*4..+3.
// Mask channel-0 pulled once into LDS and written through compactly.
__global__ __launch_bounds__(1024, 8) void k_pool(const float* __restrict__ qd,
                                                  const float* __restrict__ qm,
                                                  float* __restrict__ ws) {
    const int b = blockIdx.x >> 1, bh = blockIdx.x & 1;
    const int tid = threadIdx.x;
    const int row0 = bh * 1024;

    __shared__ float smask[1024];
    __shared__ float wsum[16];
    __shared__ float red[64][64];

    // ---- phase 1: compact mask (channel-0, 256B stride), write-through
    const float m0 = qm[((size_t)b * NN + row0 + tid) * CC];
    smask[tid] = m0;
    ws[WS_MASK + (size_t)b * NN + row0 + tid] = m0;
    float msum = m0;
    for (int off = 32; off > 0; off >>= 1) msum += __shfl_down(msum, off, 64);
    if ((tid & 63) == 0) wsum[tid >> 6] = msum;
    __syncthreads();

    // ---- phase 2: sequential sweep of the 256KB slab, two 8-deep batches
    const float4* qb4 = (const float4*)(qd + ((size_t)b * NN + row0) * CC);
    const int rbase = tid >> 4;  // row-within-step
    float4 acc = {0.f, 0.f, 0.f, 0.f};
#pragma unroll
    for (int half = 0; half < 2; ++half) {
        float4 v[8];
#pragma unroll
        for (int j = 0; j < 8; ++j)
            v[j] = qb4[(size_t)(half * 8 + j) * 1024 + tid];  // max 15*1024+1023 = 16383
#pragma unroll
        for (int j = 0; j < 8; ++j) {
            const float m = smask[(half * 8 + j) * 64 + rbase];  // max 15*64+63 = 1023
            acc.x += m * v[j].x; acc.y += m * v[j].y;
            acc.z += m * v[j].z; acc.w += m * v[j].w;
        }
    }
    // thread (rbase, c4) holds channels c4*4..+3 summed over its 16 rows
    *(float4*)&red[rbase][(tid & 15) * 4] = acc;
    __syncthreads();
    if (tid < 64) {
        float s = 0.f;
#pragma unroll
        for (int g = 0; g < 64; ++g) s += red[g][tid];
        ws[WS_SUMQ + (size_t)(b * 2 + bh) * 64 + tid] = s;
    }
    if (tid == 0) {
        float s = 0.f;
#pragma unroll
        for (int g = 0; g < 16; ++g) s += wsum[g];
        ws[WS_SUMM + b * 2 + bh] = s;
    }
}

// ---------------- K2: attention (qproj fused; 1024-row slabs) ----------------
// Same stream-count fix: 512 blocks x 1024 thr, one row/thread, contiguous
// 256KB m_data slab per block. P/V share one padded LDS array [1024][17]
// (stride 17 words, gcd(17,32)=1 -> conflict-free).
__global__ __launch_bounds__(1024) void k_attn(const float* __restrict__ md,
                                               const float* __restrict__ qw,
                                               const float* __restrict__ kw,
                                               const float* __restrict__ vw,
                                               float* __restrict__ ws) {
    const int b = blockIdx.x >> 1, nhalf = blockIdx.x & 1;
    const int tid = threadIdx.x;

    __shared__ float qa[64], ql[64];
    __shared__ float wkv[64][16];   // [c][0..7]=kq, [c][8..15]=vw
    __shared__ float PV[1024][17];  // [n][0..7]=P, [n][8..15]=v-proj, [16]=pad
    __shared__ float partV[16][64];
    __shared__ float partS[16][8];

    // ---- issue first half of this thread's row loads early
    const int n = nhalf * 1024 + tid;
    const float* rowp = md + ((size_t)b * NN + n) * CC;
    const float mk = ws[WS_MASK + (size_t)b * NN + n];
    float4 buf[8];
#pragma unroll
    for (int j = 0; j < 8; ++j) buf[j] = ((const float4*)rowp)[j];

    // ---- prologue: q_avg -> q -> kq
    if (tid < 64) {
        const float s = ws[WS_SUMQ + (size_t)(b * 2 + 0) * 64 + tid] +
                        ws[WS_SUMQ + (size_t)(b * 2 + 1) * 64 + tid];
        const float den = ws[WS_SUMM + b * 2 + 0] + ws[WS_SUMM + b * 2 + 1];
        qa[tid] = s / (den + 1e-10f);
    }
    __syncthreads();
    if (tid < 64) {
        float s = 0.f;
#pragma unroll
        for (int c = 0; c < 64; ++c) s += qa[c] * qw[c * 64 + tid];
        ql[tid] = s * 0.35355339059327373f;  // KD^-0.5, KD=8
    }
    __syncthreads();
    if (tid < 512) {
        const int c = tid >> 3, h = tid & 7;
        float s = 0.f;
#pragma unroll
        for (int d = 0; d < 8; ++d) s += kw[c * 8 + d] * ql[h * 8 + d];
        wkv[c][h] = s;
        wkv[c][8 + h] = vw[tid];  // tid = c*8+h -> vw[c][h]
    }
    __syncthreads();

    // ---- phase A: logits + v-projection for this thread's row
    float la[8], va[8];
#pragma unroll
    for (int h = 0; h < 8; ++h) { la[h] = 0.f; va[h] = 0.f; }
#pragma unroll
    for (int hv = 0; hv < 2; ++hv) {
        if (hv == 1) {
#pragma unroll
            for (int j = 0; j < 8; ++j) buf[j] = ((const float4*)rowp)[8 + j];
        }
#pragma unroll
        for (int j = 0; j < 8; ++j) {
            const float xa[4] = {buf[j].x, buf[j].y, buf[j].z, buf[j].w};
#pragma unroll
            for (int q = 0; q < 4; ++q) {
                const int c = hv * 32 + j * 4 + q;
                const float4* wr = (const float4*)wkv[c];  // broadcast reads
                const float4 wa = wr[0], wb = wr[1], wc = wr[2], wd = wr[3];
                const float x = xa[q];
                la[0] += x * wa.x; la[1] += x * wa.y; la[2] += x * wa.z; la[3] += x * wa.w;
                la[4] += x * wb.x; la[5] += x * wb.y; la[6] += x * wb.z; la[7] += x * wb.w;
                va[0] += x * wc.x; va[1] += x * wc.y; va[2] += x * wc.z; va[3] += x * wc.w;
                va[4] += x * wd.x; va[5] += x * wd.y; va[6] += x * wd.z; va[7] += x * wd.w;
            }
        }
    }

#pragma unroll
    for (int h = 0; h < 8; ++h) PV[tid][h] = mk * __expf(la[h]);  // masked rows -> 0
#pragma unroll
    for (int d = 0; d < 8; ++d) PV[tid][8 + d] = va[d];
    __syncthreads();

    // ---- phase B: reduce 1024 rows -> per-half S[h], V[h][d]
    const int w = tid >> 6, lane = tid & 63, h = lane >> 3, d = lane & 7;
    float acc = 0.f, sacc = 0.f;
    for (int i = 0; i < 64; ++i) {
        const int rr = w * 64 + i;
        const float p = PV[rr][h];  // broadcast reads, conflict-free
        acc += p * PV[rr][8 + d];
        sacc += p;
    }
    partV[w][lane] = acc;
    if (d == 0) partS[w][h] = sacc;
    __syncthreads();
    if (tid < 64) {
        float s = 0.f;
#pragma unroll
        for (int g = 0; g < 16; ++g) s += partV[g][tid];
        ws[WS_V + (size_t)(b * 2 + nhalf) * 64 + tid] = s;
    }
    if (tid < 8) {
        float s = 0.f;
#pragma unroll
        for (int g = 0; g < 16; ++g) s += partS[g][tid];
        ws[WS_S + (size_t)(b * 2 + nhalf) * 8 + tid] = s;
    }
}

// ---------------- K3: gate = sigmoid(q_data@Gw + gb); out = (gate*wavg)@Ow + ob ----
// MFMA 16x16x32 bf16. Unchanged except the prologue sums 2 per-half V/S partials.
__global__ __launch_bounds__(256) void k_out(const float* __restrict__ qd,
                                             const float* __restrict__ ow,
                                             const float* __restrict__ obias,
                                             const float* __restrict__ gw,
                                             const float* __restrict__ gb,
                                             const float* __restrict__ ws,
                                             float* __restrict__ out) {
    const int b = blockIdx.x >> 3, chunk = blockIdx.x & 7;
    const int tid = threadIdx.x;
    const int w = tid >> 6, lane = tid & 63, q16 = lane >> 4, c16 = lane & 15;

    __shared__ float s_wavg[64], s_sden[8];
    if (tid < 64) {
        s_wavg[tid] = ws[WS_V + (size_t)(b * 2 + 0) * 64 + tid] +
                      ws[WS_V + (size_t)(b * 2 + 1) * 64 + tid];
    }
    if (tid >= 64 && tid < 72) {
        const int hh = tid - 64;
        s_sden[hh] = ws[WS_S + (size_t)(b * 2 + 0) * 8 + hh] +
                     ws[WS_S + (size_t)(b * 2 + 1) * 8 + hh];
    }
    __syncthreads();

    // Per-wave constant B-fragments: Gw (gating weights) and W2 = wavg ⊙ Ow
    bf16x8 gwf[2][4], w2f[2][4];
    float gbv[4], obv[4];
#pragma unroll
    for (int kc = 0; kc < 2; ++kc) {
        const int k0 = kc * 32 + q16 * 8;
        const float inv_s = 1.f / s_sden[k0 >> 3];  // same h for all 8 j's
#pragma unroll
        for (int t = 0; t < 4; ++t) {
            const int n2 = t * 16 + c16;
            bf16x8 gf, wf;
#pragma unroll
            for (int j = 0; j < 8; ++j) {
                gf[j] = (__bf16)gw[(size_t)(k0 + j) * 64 + n2];
                wf[j] = (__bf16)(s_wavg[k0 + j] * inv_s *
                                 ow[(size_t)(k0 + j) * 64 + n2]);
            }
            gwf[kc][t] = gf;
            w2f[kc][t] = wf;
        }
    }
#pragma unroll
    for (int t = 0; t < 4; ++t) {
        gbv[t] = gb[t * 16 + c16];
        obv[t] = obias[t * 16 + c16];
    }

    // C-layout -> A-layout transpose buffer; wave-private region gl[w];
    // row padded 64->72 bf16 (144B) to spread banks
    __shared__ __align__(16) __bf16 gl[4][16][72];

    const size_t base_row = (size_t)b * NN + chunk * 256 + w * 16;

    float4 cur0, cur1, cur2, cur3, nxt0, nxt1, nxt2, nxt3;
    {
        const float* arow = qd + (base_row + c16) * CC;
        cur0 = *(const float4*)(arow + q16 * 8);
        cur1 = *(const float4*)(arow + q16 * 8 + 4);
        cur2 = *(const float4*)(arow + 32 + q16 * 8);
        cur3 = *(const float4*)(arow + 32 + q16 * 8 + 4);
    }

    for (int s = 0; s < 4; ++s) {
        if (s < 3) {  // prefetch next slab
            const float* arow = qd + (base_row + (s + 1) * 64 + c16) * CC;
            nxt0 = *(const float4*)(arow + q16 * 8);
            nxt1 = *(const float4*)(arow + q16 * 8 + 4);
            nxt2 = *(const float4*)(arow + 32 + q16 * 8);
            nxt3 = *(const float4*)(arow + 32 + q16 * 8 + 4);
        }
        bf16x8 af[2];
        {
            bf16x8 a;
            a[0] = (__bf16)cur0.x; a[1] = (__bf16)cur0.y; a[2] = (__bf16)cur0.z; a[3] = (__bf16)cur0.w;
            a[4] = (__bf16)cur1.x; a[5] = (__bf16)cur1.y; a[6] = (__bf16)cur1.z; a[7] = (__bf16)cur1.w;
            af[0] = a;
            a[0] = (__bf16)cur2.x; a[1] = (__bf16)cur2.y; a[2] = (__bf16)cur2.z; a[3] = (__bf16)cur2.w;
            a[4] = (__bf16)cur3.x; a[5] = (__bf16)cur3.y; a[6] = (__bf16)cur3.z; a[7] = (__bf16)cur3.w;
            af[1] = a;
        }
        f32x4 accg[4] = {{0.f, 0.f, 0.f, 0.f}, {0.f, 0.f, 0.f, 0.f},
                         {0.f, 0.f, 0.f, 0.f}, {0.f, 0.f, 0.f, 0.f}};
#pragma unroll
        for (int kc = 0; kc < 2; ++kc)
#pragma unroll
            for (int t = 0; t < 4; ++t)
                accg[t] = __builtin_amdgcn_mfma_f32_16x16x32_bf16(af[kc], gwf[kc][t],
                                                                  accg[t], 0, 0, 0);
        // sigmoid + stash in A-operand order (wave-private LDS region)
#pragma unroll
        for (int t = 0; t < 4; ++t)
#pragma unroll
            for (int r2 = 0; r2 < 4; ++r2) {
                const float x = accg[t][r2] + gbv[t];
                const float g = 1.f / (1.f + __expf(-x));
                gl[w][q16 * 4 + r2][t * 16 + c16] = (__bf16)g;
            }
        __asm__ volatile("s_waitcnt lgkmcnt(0)" ::: "memory");
        bf16x8 a2[2];
#pragma unroll
        for (int kc = 0; kc < 2; ++kc)
            a2[kc] = *(const bf16x8*)&gl[w][c16][kc * 32 + q16 * 8];
        f32x4 acco[4] = {{0.f, 0.f, 0.f, 0.f}, {0.f, 0.f, 0.f, 0.f},
                         {0.f, 0.f, 0.f, 0.f}, {0.f, 0.f, 0.f, 0.f}};
#pragma unroll
        for (int kc = 0; kc < 2; ++kc)
#pragma unroll
            for (int t = 0; t < 4; ++t)
                acco[t] = __builtin_amdgcn_mfma_f32_16x16x32_bf16(a2[kc], w2f[kc][t],
                                                                  acco[t], 0, 0, 0);
        __asm__ volatile("s_waitcnt lgkmcnt(0)" ::: "memory");  // reads done before next slab's writes
        float* orow = out + (base_row + s * 64) * CC;
#pragma unroll
        for (int t = 0; t < 4; ++t)
#pragma unroll
            for (int r2 = 0; r2 < 4; ++r2)
                orow[(size_t)(q16 * 4 + r2) * 64 + t * 16 + c16] = acco[t][r2] + obv[t];
        cur0 = nxt0; cur1 = nxt1; cur2 = nxt2; cur3 = nxt3;
    }
}

extern "C" void kernel_launch(void* const* d_in, const int* in_sizes, int n_in,
                              void* d_out, int out_size, void* d_ws, size_t ws_size,
                              hipStream_t stream) {
    const float* q_data = (const float*)d_in[0];
    const float* m_data = (const float*)d_in[1];
    const float* q_mask = (const float*)d_in[2];
    // d_in[3] = bias, ignored by the forward (AF2 quirk)
    const float* q_w = (const float*)d_in[4];
    const float* k_w = (const float*)d_in[5];
    const float* v_w = (const float*)d_in[6];
    const float* o_w = (const float*)d_in[7];
    const float* o_b = (const float*)d_in[8];
    const float* g_w = (const float*)d_in[9];
    const float* g_b = (const float*)d_in[10];
    float* out = (float*)d_out;
    float* ws = (float*)d_ws;

    // no memset: every ws region is written (non-atomically) before it is read
    hipLaunchKernelGGL(k_pool, dim3(BN * 2), dim3(1024), 0, stream, q_data, q_mask, ws);
    hipLaunchKernelGGL(k_attn, dim3(BN * 2), dim3(1024), 0, stream, m_data, q_w, k_w,
                       v_w, ws);
    hipLaunchKernelGGL(k_out, dim3(BN * 8), dim3(256), 0, stream, q_data, o_w, o_b,
                       g_w, g_b, ws, out);
}

// Round 5
// 437.083 us; speedup vs baseline: 1.0370x; 1.0370x over previous
//
#include <hip/hip_runtime.h>
#include <hip/hip_bf16.h>
#include <math.h>

#define BN 256
#define NN 2048
#define CC 64

typedef __bf16 bf16x8 __attribute__((ext_vector_type(8)));
typedef float f32x4 __attribute__((ext_vector_type(4)));

// ============ single fused kernel: block b owns batch b entirely ============
// 256 blocks x 1024 threads (16 waves), 1 block/CU.
// Phase 0: stage mask channel-0 (2048 rows) into LDS.
// Phase 1: masked pool of q_data[b] (512KB contiguous sweep).
// Phase 2: q_avg -> q -> kq (tiny, threads 0..511).
// Phase 3: attention: 2 passes x 1024 rows of m_data[b]; P/V staged in LDS,
//          block-reduced to S[8], V[64].
// Phase 4: gate = sigmoid(q_data@Gw+gb) via MFMA; out = (gate*wavg)@Ow + ob.
//          B-fragments read from LDS (bf16, XOR-swizzled granules) to keep
//          VGPR <= 128 (hard requirement for a 1024-thread block).
// LDS ~101 KB. PVpool is reused: phase-1 red[64][64] / phase-3 PV[1024][17] /
// phase-4 gl[16][16][72] transpose buffer (all separated by syncthreads).
__global__ __launch_bounds__(1024, 4) void k_fused(
    const float* __restrict__ qd, const float* __restrict__ md,
    const float* __restrict__ qm, const float* __restrict__ qw,
    const float* __restrict__ kw, const float* __restrict__ vw,
    const float* __restrict__ ow, const float* __restrict__ obias,
    const float* __restrict__ gw, const float* __restrict__ gb,
    float* __restrict__ out) {
    const int b = blockIdx.x;
    const int tid = threadIdx.x;

    __shared__ float smask[2048];                       // 8 KB
    __shared__ __align__(16) float PVpool[1024 * 17];   // 68 KB (red / PV / gl)
    __shared__ float wkv[64][16];                       // 4 KB
    __shared__ float partV[16][64];                     // 4 KB
    __shared__ float partS[16][8];
    __shared__ float qa[64], ql[64];
    __shared__ float s_wavg[64], s_sden[8];
    __shared__ __align__(16) __bf16 gwT[4096];          // 8 KB, swizzled [n][k]
    __shared__ __align__(16) __bf16 w2T[4096];          // 8 KB, swizzled [n][k]

#define PVF(n, j) PVpool[(n) * 17 + (j)]
#define RED(g, c) PVpool[(g) * 64 + (c)]

    // ---- phase 0: mask channel-0 (stride 256B) into LDS
    smask[tid] = qm[((size_t)b * NN + tid) * CC];
    smask[tid + 1024] = qm[((size_t)b * NN + tid + 1024) * CC];
    __syncthreads();

    // ---- phase 1: masked pool, sequential 512KB sweep, 8-deep batches
    {
        const float4* qb4 = (const float4*)(qd + (size_t)b * NN * CC);
        const int rbase = tid >> 4;  // row-within-step
        float4 acc = {0.f, 0.f, 0.f, 0.f};
        for (int g4 = 0; g4 < 4; ++g4) {
            float4 v[8];
#pragma unroll
            for (int j = 0; j < 8; ++j)
                v[j] = qb4[(size_t)(g4 * 8 + j) * 1024 + tid];  // max 32767
#pragma unroll
            for (int j = 0; j < 8; ++j) {
                const float m = smask[(g4 * 8 + j) * 64 + rbase];  // max 2047
                acc.x += m * v[j].x; acc.y += m * v[j].y;
                acc.z += m * v[j].z; acc.w += m * v[j].w;
            }
        }
        *(float4*)&RED(rbase, (tid & 15) * 4) = acc;
    }
    __syncthreads();

    // ---- phase 2: q_avg -> q(scaled) -> kq + vw staging
    if (tid < 64) {
        float den = 0.f;
        for (int g = 0; g < 32; ++g) den += smask[tid + g * 64];
        for (int off = 1; off < 64; off <<= 1) den += __shfl_xor(den, off, 64);
        float s = 0.f;
        for (int g = 0; g < 64; ++g) s += RED(g, tid);
        qa[tid] = s / (den + 1e-10f);
    }
    __syncthreads();
    if (tid < 64) {
        float s = 0.f;
#pragma unroll
        for (int c = 0; c < 64; ++c) s += qa[c] * qw[c * 64 + tid];
        ql[tid] = s * 0.35355339059327373f;  // KD^-0.5, KD=8
    }
    __syncthreads();
    if (tid < 512) {
        const int c = tid >> 3, h = tid & 7;
        float s = 0.f;
#pragma unroll
        for (int d = 0; d < 8; ++d) s += kw[c * 8 + d] * ql[h * 8 + d];
        wkv[c][h] = s;
        wkv[c][8 + h] = vw[tid];  // vw[c][h]
    }
    __syncthreads();

    // ---- phase 3: attention over m_data[b], 2 passes x 1024 rows
    float vreg = 0.f, sreg = 0.f;  // accumulated by tid<64 / tid<8
    for (int pass = 0; pass < 2; ++pass) {
        const int row = pass * 1024 + tid;
        const float mk = smask[row];
        const float4* rowp4 = (const float4*)(md + ((size_t)b * NN + row) * CC);
        float la[8], va[8];
#pragma unroll
        for (int h = 0; h < 8; ++h) { la[h] = 0.f; va[h] = 0.f; }
#pragma unroll
        for (int hv = 0; hv < 2; ++hv) {
            float4 buf[8];
#pragma unroll
            for (int j = 0; j < 8; ++j) buf[j] = rowp4[hv * 8 + j];
#pragma unroll
            for (int j = 0; j < 8; ++j) {
                const float xa[4] = {buf[j].x, buf[j].y, buf[j].z, buf[j].w};
#pragma unroll
                for (int q = 0; q < 4; ++q) {
                    const int c = hv * 32 + j * 4 + q;
                    const float4* wr = (const float4*)wkv[c];  // broadcast
                    const float4 wa = wr[0], wb = wr[1], wc = wr[2], wd = wr[3];
                    const float x = xa[q];
                    la[0] += x * wa.x; la[1] += x * wa.y; la[2] += x * wa.z; la[3] += x * wa.w;
                    la[4] += x * wb.x; la[5] += x * wb.y; la[6] += x * wb.z; la[7] += x * wb.w;
                    va[0] += x * wc.x; va[1] += x * wc.y; va[2] += x * wc.z; va[3] += x * wc.w;
                    va[4] += x * wd.x; va[5] += x * wd.y; va[6] += x * wd.z; va[7] += x * wd.w;
                }
            }
        }
#pragma unroll
        for (int h = 0; h < 8; ++h) PVF(tid, h) = mk * __expf(la[h]);
#pragma unroll
        for (int d = 0; d < 8; ++d) PVF(tid, 8 + d) = va[d];
        __syncthreads();
        {
            const int w = tid >> 6, lane = tid & 63, h = lane >> 3, d = lane & 7;
            float a2 = 0.f, s2 = 0.f;
            for (int i = 0; i < 64; ++i) {
                const int rr = w * 64 + i;
                const float p = PVF(rr, h);
                a2 += p * PVF(rr, 8 + d);
                s2 += p;
            }
            partV[w][lane] = a2;
            if (d == 0) partS[w][h] = s2;
        }
        __syncthreads();
        if (tid < 64) {
            float s = 0.f;
#pragma unroll
            for (int g = 0; g < 16; ++g) s += partV[g][tid];
            vreg += s;
        }
        if (tid < 8) {
            float s = 0.f;
#pragma unroll
            for (int g = 0; g < 16; ++g) s += partS[g][tid];
            sreg += s;
        }
        __syncthreads();  // PV + partV reads done before pass-1 overwrite
    }
    if (tid < 64) s_wavg[tid] = vreg;
    if (tid < 8) s_sden[tid] = sreg;
    __syncthreads();

    // ---- phase 4 prep: stage Gw and W2=wavg/S ⊙ Ow as bf16, XOR-swizzled.
    // Element (k,n) -> index n*64 + (((k>>3)^(n&7))<<3) + (k&7); bijective per
    // row; frag read = contiguous bf16x8 granule, banks spread across lanes.
    {
        const int k = tid >> 4;
        const int n0 = (tid & 15) * 4;
        const float wv = s_wavg[k] / s_sden[k >> 3];
#pragma unroll
        for (int u = 0; u < 4; ++u) {
            const int n = n0 + u;
            const int idx = n * 64 + ((((k >> 3) ^ (n & 7))) << 3) + (k & 7);
            gwT[idx] = (__bf16)gw[(size_t)k * 64 + n];
            w2T[idx] = (__bf16)(wv * ow[(size_t)k * 64 + n]);
        }
    }
    const int w = tid >> 6, lane = tid & 63, q16 = lane >> 4, c16 = lane & 15;
    float gbv[4], obv[4];
#pragma unroll
    for (int t = 0; t < 4; ++t) {
        gbv[t] = gb[t * 16 + c16];
        obv[t] = obias[t * 16 + c16];
    }
    __syncthreads();  // gwT/w2T ready; all PVpool reads retired -> gl alias safe

    // ---- phase 4: wave w owns rows w*128..w*128+127, 8 slabs of 16 rows.
    __bf16* gl = (__bf16*)PVpool;  // [16][16][72] view, wave-private slice
#define GL(wv, r, c) gl[(((wv)*16 + (r)) * 72) + (c)]
    const size_t base_row = (size_t)b * NN + (size_t)w * 128;

    float4 cur0, cur1, cur2, cur3, nxt0, nxt1, nxt2, nxt3;
    {
        const float* arow = qd + (base_row + c16) * CC;
        cur0 = *(const float4*)(arow + q16 * 8);
        cur1 = *(const float4*)(arow + q16 * 8 + 4);
        cur2 = *(const float4*)(arow + 32 + q16 * 8);
        cur3 = *(const float4*)(arow + 32 + q16 * 8 + 4);
    }

    for (int s = 0; s < 8; ++s) {
        if (s < 7) {  // prefetch next slab
            const float* arow = qd + (base_row + (s + 1) * 16 + c16) * CC;
            nxt0 = *(const float4*)(arow + q16 * 8);
            nxt1 = *(const float4*)(arow + q16 * 8 + 4);
            nxt2 = *(const float4*)(arow + 32 + q16 * 8);
            nxt3 = *(const float4*)(arow + 32 + q16 * 8 + 4);
        }
        bf16x8 af[2];
        {
            bf16x8 a;
            a[0] = (__bf16)cur0.x; a[1] = (__bf16)cur0.y; a[2] = (__bf16)cur0.z; a[3] = (__bf16)cur0.w;
            a[4] = (__bf16)cur1.x; a[5] = (__bf16)cur1.y; a[6] = (__bf16)cur1.z; a[7] = (__bf16)cur1.w;
            af[0] = a;
            a[0] = (__bf16)cur2.x; a[1] = (__bf16)cur2.y; a[2] = (__bf16)cur2.z; a[3] = (__bf16)cur2.w;
            a[4] = (__bf16)cur3.x; a[5] = (__bf16)cur3.y; a[6] = (__bf16)cur3.z; a[7] = (__bf16)cur3.w;
            af[1] = a;
        }
        f32x4 accg[4] = {{0.f, 0.f, 0.f, 0.f}, {0.f, 0.f, 0.f, 0.f},
                         {0.f, 0.f, 0.f, 0.f}, {0.f, 0.f, 0.f, 0.f}};
#pragma unroll
        for (int kc = 0; kc < 2; ++kc) {
            bf16x8 bf[4];
#pragma unroll
            for (int t = 0; t < 4; ++t) {
                const int n = t * 16 + c16;
                bf[t] = *(const bf16x8*)&gwT[n * 64 + (((kc * 4 + q16) ^ (n & 7)) << 3)];
            }
#pragma unroll
            for (int t = 0; t < 4; ++t)
                accg[t] = __builtin_amdgcn_mfma_f32_16x16x32_bf16(af[kc], bf[t],
                                                                  accg[t], 0, 0, 0);
        }
        // sigmoid + stash in A-operand order (wave-private LDS region)
#pragma unroll
        for (int t = 0; t < 4; ++t)
#pragma unroll
            for (int r2 = 0; r2 < 4; ++r2) {
                const float x = accg[t][r2] + gbv[t];
                const float g = 1.f / (1.f + __expf(-x));
                GL(w, q16 * 4 + r2, t * 16 + c16) = (__bf16)g;
            }
        __asm__ volatile("s_waitcnt lgkmcnt(0)" ::: "memory");
        bf16x8 a2[2];
#pragma unroll
        for (int kc = 0; kc < 2; ++kc)
            a2[kc] = *(const bf16x8*)&GL(w, c16, kc * 32 + q16 * 8);
        f32x4 acco[4] = {{0.f, 0.f, 0.f, 0.f}, {0.f, 0.f, 0.f, 0.f},
                         {0.f, 0.f, 0.f, 0.f}, {0.f, 0.f, 0.f, 0.f}};
#pragma unroll
        for (int kc = 0; kc < 2; ++kc) {
            bf16x8 bf[4];
#pragma unroll
            for (int t = 0; t < 4; ++t) {
                const int n = t * 16 + c16;
                bf[t] = *(const bf16x8*)&w2T[n * 64 + (((kc * 4 + q16) ^ (n & 7)) << 3)];
            }
#pragma unroll
            for (int t = 0; t < 4; ++t)
                acco[t] = __builtin_amdgcn_mfma_f32_16x16x32_bf16(a2[kc], bf[t],
                                                                  acco[t], 0, 0, 0);
        }
        __asm__ volatile("s_waitcnt lgkmcnt(0)" ::: "memory");  // a2 reads done before next slab's GL writes
        float* orow = out + (base_row + s * 16) * CC;
#pragma unroll
        for (int t = 0; t < 4; ++t)
#pragma unroll
            for (int r2 = 0; r2 < 4; ++r2)
                orow[(size_t)(q16 * 4 + r2) * 64 + t * 16 + c16] = acco[t][r2] + obv[t];
        cur0 = nxt0; cur1 = nxt1; cur2 = nxt2; cur3 = nxt3;
    }
#undef GL
#undef PVF
#undef RED
}

extern "C" void kernel_launch(void* const* d_in, const int* in_sizes, int n_in,
                              void* d_out, int out_size, void* d_ws, size_t ws_size,
                              hipStream_t stream) {
    const float* q_data = (const float*)d_in[0];
    const float* m_data = (const float*)d_in[1];
    const float* q_mask = (const float*)d_in[2];
    // d_in[3] = bias, ignored by the forward (AF2 quirk)
    const float* q_w = (const float*)d_in[4];
    const float* k_w = (const float*)d_in[5];
    const float* v_w = (const float*)d_in[6];
    const float* o_w = (const float*)d_in[7];
    const float* o_b = (const float*)d_in[8];
    const float* g_w = (const float*)d_in[9];
    const float* g_b = (const float*)d_in[10];
    float* out = (float*)d_out;
    (void)d_ws; (void)ws_size; (void)in_sizes; (void)n_in; (void)out_size;

    // one launch: block b handles batch b end-to-end (no workspace, no memset)
    hipLaunchKernelGGL(k_fused, dim3(BN), dim3(1024), 0, stream, q_data, m_data,
                       q_mask, q_w, k_w, v_w, o_w, o_b, g_w, g_b, out);
}